// Round 1
// baseline (778.081 us; speedup 1.0000x reference)
//
#include <hip/hip_runtime.h>

// ---------------- problem constants ----------------
constexpr int cB  = 2;
constexpr int cNR = 16384;
constexpr int cNP = 65536;
constexpr int cE  = 262144;
constexpr int cF  = 128;
constexpr int SP  = 136;   // bf16 row stride in LDS (2-way bank aliasing = free)
constexpr int EFP = 40;    // padded edge-feature row stride (K=4 -> 32 pad)

typedef unsigned short u16;
using f32x4 = __attribute__((ext_vector_type(4))) float;
using s8v   = __attribute__((ext_vector_type(8))) short;

// ws layout (float offsets): agg bf16 [B][NP][128] (33.5 MB), cnt f32 [B][NP],
// ss (3x[B,256]), swizzled weights, rnode bf16, pnode bf16.
constexpr size_t WS_CNT = ((size_t)cB * cNP * cF) / 2;
constexpr size_t WS_SS  = WS_CNT + (size_t)cB * cNP;
constexpr size_t WS_WB  = WS_SS + 3 * cB * 256;

// swizzled-weight segment bases (units of k8 = 8 K-rows; one k8 = 1024 u16)
constexpr int G8_We2 = 0, G8_Wu1 = 16, G8_Wu2 = 64, G8_Wp1 = 80, G8_Wp2 = 112, G8_Wo1 = 128;
constexpr int G8_TOT = 144;
// after main: Wo2 (K=128, N=16-padded): 256 uint4 ; We1 (K=32-padded): 512 uint4
constexpr int SWZ_N = G8_TOT * 128 + 256 + 512;      // uint4 elements (threads)
constexpr int WB_WE1 = (G8_TOT * 128 + 256) * 8;     // u16 offset of We1 block
// bf16 copies AFTER weight buffer
constexpr size_t WS_RB = WS_WB + (size_t)SWZ_N * 4;                  // rnode bf16
constexpr size_t WS_PB = WS_RB + (size_t)cB * cNR * cF / 2;          // pnode bf16

// ---------------- helpers ----------------
__device__ __forceinline__ float bf2f(u16 u) {
  union { unsigned int i; float f; } v; v.i = ((unsigned int)u) << 16; return v.f;
}
__device__ __forceinline__ u16 f2bf(float f) {        // RNE (weights only)
  union { float f; unsigned int i; } v; v.f = f;
  unsigned int x = v.i;
  return (u16)((x + 0x7fffu + ((x >> 16) & 1u)) >> 16);
}
// fast round-half-up bf16 (intermediates; 2 VALU ops)
__device__ __forceinline__ u16 f2bf_fast(float f) {
  return (u16)((__float_as_uint(f) + 0x8000u) >> 16);
}
// packed pair via v_perm_b32 (3 VALU ops total): low=bf16(a), high=bf16(b)
__device__ __forceinline__ unsigned pack2(float a, float b) {
  return __builtin_amdgcn_perm(__float_as_uint(b) + 0x8000u,
                               __float_as_uint(a) + 0x8000u, 0x07060302u);
}
// swish via single v_rcp_f32 (1-ulp)
__device__ __forceinline__ float swishf(float x) {
  return x * __builtin_amdgcn_rcpf(1.0f + __expf(-x));
}

// DPP add: x += dpp<CTRL>(x). Pure VALU (no LGKM). CTRL must be constexpr.
template <int CTRL>
__device__ __forceinline__ float dpp_add(float x) {
  int xi = __float_as_int(x);
  int r = __builtin_amdgcn_update_dpp(xi, xi, CTRL, 0xf, 0xf, false);
  return x + __int_as_float(r);
}
// value of lane^1 via DPP quad_perm(1,0,3,2)
__device__ __forceinline__ float dpp_xor1(float x) {
  int xi = __float_as_int(x);
  int r = __builtin_amdgcn_update_dpp(xi, xi, 0xB1, 0xf, 0xf, false);
  return __int_as_float(r);
}

// packed bf16x2 atomic add (global_atomic_pk_add_bf16, gfx950)
__device__ __forceinline__ void atomic_pk_bf16(u16* addr, float lo, float hi) {
  unsigned data = pack2(lo, hi);
  unsigned long long a = (unsigned long long)addr;
  asm volatile("global_atomic_pk_add_bf16 %0, %1, off" :: "v"(a), "v"(data) : "memory");
}

// direct global->LDS DMA: 4B per lane, dest = uniform base + lane*4
__device__ __forceinline__ void gload4_lds(const u16* gsrc, u16* lds) {
  __builtin_amdgcn_global_load_lds(
      (const __attribute__((address_space(1))) void*)gsrc,
      (__attribute__((address_space(3))) void*)lds, 4, 0, 0);
}

// ---- column-strip MFMA pass: wave covers rows 0..63 x 32-col strip (cw) ----
__device__ __forceinline__ void kloop128s(const u16* act, const u16* __restrict__ wbg,
                                          f32x4 (&acc)[4][2], int cw, int l16, int quad) {
  s8v bf[4][2];
#pragma unroll
  for (int k0 = 0; k0 < 4; ++k0)
#pragma unroll
    for (int ci = 0; ci < 2; ++ci)
      bf[k0][ci] = *(const s8v*)(wbg + ((size_t)(k0 * 4 + quad) * 128 + cw + ci * 16 + l16) * 8);
#pragma unroll
  for (int k0 = 0; k0 < 4; ++k0) {
    s8v af[4];
#pragma unroll
    for (int ri = 0; ri < 4; ++ri)
      af[ri] = *(const s8v*)(act + (size_t)(ri * 16 + l16) * SP + k0 * 32 + quad * 8);
#pragma unroll
    for (int ri = 0; ri < 4; ++ri)
#pragma unroll
      for (int ci = 0; ci < 2; ++ci)
        acc[ri][ci] = __builtin_amdgcn_mfma_f32_16x16x32_bf16(af[ri], bf[k0][ci], acc[ri][ci], 0, 0, 0);
  }
}

__device__ __forceinline__ void init_acc_s(f32x4 (&acc)[4][2], const float* __restrict__ bias,
                                           int cw, int l16) {
#pragma unroll
  for (int ci = 0; ci < 2; ++ci) {
    float bv = bias[cw + ci * 16 + l16];
#pragma unroll
    for (int ri = 0; ri < 4; ++ri) acc[ri][ci] = (f32x4){bv, bv, bv, bv};
  }
}

// conditioned LayerNorm on strip C-layout; 16-lane reduce via DPP row_ror (VALU only)
__device__ __forceinline__ void cond_norm_s(f32x4 (&acc)[4][2], float* red, float* musig,
                                            const float* __restrict__ ssp,
                                            int cw, int l16, int quad, int wv, int t) {
  __syncthreads();                 // prior LDS reads done; red/musig reuse safe
#pragma unroll
  for (int ri = 0; ri < 4; ++ri)
#pragma unroll
    for (int reg = 0; reg < 4; ++reg) {
      float v0 = acc[ri][0][reg], v1 = acc[ri][1][reg];
      float s = v0 + v1;
      float q = v0 * v0 + v1 * v1;
      s = dpp_add<0x128>(s); q = dpp_add<0x128>(q);   // row_ror:8
      s = dpp_add<0x124>(s); q = dpp_add<0x124>(q);   // row_ror:4
      s = dpp_add<0x122>(s); q = dpp_add<0x122>(q);   // row_ror:2
      s = dpp_add<0x121>(s); q = dpp_add<0x121>(q);   // row_ror:1
      if (l16 == 0) {
        int row = ri * 16 + quad * 4 + reg;
        red[row * 8 + wv * 2]     = s;
        red[row * 8 + wv * 2 + 1] = q;
      }
    }
  __syncthreads();
  if (t < 64) {
    float sum = red[t * 8 + 0] + red[t * 8 + 2] + red[t * 8 + 4] + red[t * 8 + 6];
    float sq  = red[t * 8 + 1] + red[t * 8 + 3] + red[t * 8 + 5] + red[t * 8 + 7];
    float mu  = sum * (1.0f / 128.0f);
    float var = fmaxf(sq * (1.0f / 128.0f) - mu * mu, 0.0f);
    musig[t * 2]     = mu;
    musig[t * 2 + 1] = __builtin_amdgcn_rsqf(var + 1e-6f);
  }
  __syncthreads();
  float scl[2], shf[2];
#pragma unroll
  for (int ci = 0; ci < 2; ++ci) {
    int col = cw + ci * 16 + l16;
    scl[ci] = 1.0f + ssp[col];
    shf[ci] = ssp[128 + col];
  }
#pragma unroll
  for (int ri = 0; ri < 4; ++ri)
#pragma unroll
    for (int reg = 0; reg < 4; ++reg) {
      int row = ri * 16 + quad * 4 + reg;
      float mu = musig[row * 2], is = musig[row * 2 + 1];
#pragma unroll
      for (int ci = 0; ci < 2; ++ci)
        acc[ri][ci][reg] = (acc[ri][ci][reg] - mu) * is * scl[ci] + shf[ci];
    }
}

template <bool DOSWISH>
__device__ __forceinline__ void store_s(u16* buf, const f32x4 (&acc)[4][2],
                                        int cw, int l16, int quad) {
#pragma unroll
  for (int ri = 0; ri < 4; ++ri)
#pragma unroll
    for (int reg = 0; reg < 4; ++reg) {
      int row = ri * 16 + quad * 4 + reg;
#pragma unroll
      for (int ci = 0; ci < 2; ++ci) {
        float v = acc[ri][ci][reg];
        if (DOSWISH) v = swishf(v);
        buf[(size_t)row * SP + cw + ci * 16 + l16] = f2bf_fast(v);
      }
    }
}

// ---------------- kernel: zero agg (bf16) + cnt (f32) ----------------
__global__ void zero_kernel(float4* __restrict__ p, int n4) {
  int i = blockIdx.x * 256 + threadIdx.x;
  if (i < n4) p[i] = make_float4(0.f, 0.f, 0.f, 0.f);
}

// ---------------- kernel: f32 -> bf16 packed copy ----------------
__global__ void cvtn_kernel(const float* __restrict__ src, u16* __restrict__ dst, int n2) {
  int i = blockIdx.x * 256 + threadIdx.x;   // u32-pair index
  if (i >= n2) return;
  float2 v = ((const float2*)src)[i];
  ((unsigned*)dst)[i] = pack2(v.x, v.y);
}

// ---------------- kernel: weight bf16 swizzle ----------------
// main: W[K][128] -> [K/8][128][8] ; Wo2[128][4] -> N=16-padded; We1[4][128] -> K=32-padded
struct SwzSrc { const float* p[7]; };  // We2, Wu1, Wu2, Wp1, Wp2, Wo1, We1

__global__ void swz_kernel(SwzSrc s, const float* __restrict__ Wo2, u16* __restrict__ wb) {
  int t = blockIdx.x * 256 + threadIdx.x;
  if (t >= SWZ_N) return;
  if (t >= G8_TOT * 128 + 256) {          // We1: K=4 zero-padded to 32
    int idx3 = t - (G8_TOT * 128 + 256);
    int k8 = idx3 >> 7, n = idx3 & 127;
    const float* We1 = s.p[6];
    u16 v[8];
#pragma unroll
    for (int j = 0; j < 8; ++j) {
      int k = k8 * 8 + j;
      v[j] = (k < 4) ? f2bf(We1[(size_t)k * 128 + n]) : (u16)0;
    }
    ((uint4*)wb)[t] = *(uint4*)v;
    return;
  }
  if (t >= G8_TOT * 128) {                // Wo2 tail
    int idx2 = t - G8_TOT * 128;
    int k8 = idx2 >> 4, n = idx2 & 15;
    u16 v[8];
#pragma unroll
    for (int j = 0; j < 8; ++j)
      v[j] = (n < 4) ? f2bf(Wo2[(size_t)(k8 * 8 + j) * 4 + n]) : (u16)0;
    ((uint4*)wb)[G8_TOT * 128 + k8 * 16 + n] = *(uint4*)v;
    return;
  }
  int n = t & 127, g8 = t >> 7;
  int seg, base;
  if (g8 < G8_Wu1)      { seg = 0; base = G8_We2; }
  else if (g8 < G8_Wu2) { seg = 1; base = G8_Wu1; }
  else if (g8 < G8_Wp1) { seg = 2; base = G8_Wu2; }
  else if (g8 < G8_Wp2) { seg = 3; base = G8_Wp1; }
  else if (g8 < G8_Wo1) { seg = 4; base = G8_Wp2; }
  else                  { seg = 5; base = G8_Wo1; }
  const float* W = s.p[seg];
  int k8l = g8 - base;
  u16 v[8];
#pragma unroll
  for (int j = 0; j < 8; ++j) v[j] = f2bf(W[(size_t)(k8l * 8 + j) * 128 + n]);
  ((uint4*)wb)[g8 * 128 + n] = *(uint4*)v;
}

// ---------------- kernel: tau-conditioned scale/shift (3 sets) ----------------
__global__ void cond_kernel(const float* __restrict__ tau,
                            const float* __restrict__ Ce1, const float* __restrict__ ce1,
                            const float* __restrict__ Ce2, const float* __restrict__ ce2,
                            const float* __restrict__ Cu1, const float* __restrict__ cu1,
                            const float* __restrict__ Cu2, const float* __restrict__ cu2,
                            const float* __restrict__ Cp1, const float* __restrict__ cp1,
                            const float* __restrict__ Cp2, const float* __restrict__ cp2,
                            float* __restrict__ ss) {
  int set = blockIdx.x, b = blockIdx.y, j = threadIdx.x;
  const float *C1, *c1, *C2, *c2;
  if (set == 0)      { C1 = Ce1; c1 = ce1; C2 = Ce2; c2 = ce2; }
  else if (set == 1) { C1 = Cu1; c1 = cu1; C2 = Cu2; c2 = cu2; }
  else               { C1 = Cp1; c1 = cp1; C2 = Cp2; c2 = cp2; }
  float tf = tau[b];
  float a = c2[j];
  for (int k = 0; k < 16; ++k) {
    float h = swishf(tf * C1[k] + c1[k]);
    a = fmaf(h, C2[k * 256 + j], a);
  }
  ss[(size_t)set * cB * 256 + (size_t)b * 256 + j] = a;
}

// ---------------- fused MFMA edge pipeline, single-LDS-buffer version ----------------
struct EWb { const float *be1, *be2, *bu1, *bu2; };

struct __align__(16) EdgeSmem {
  u16 bufX[64 * SP];            // h_embed -> sf -> rf -> e_emb -> h2
  union {
    u16 ef[64 * EFP];           // padded bf16 edge features (embed MFMA A)
    struct { float red[512]; float musig[128]; } r;
  } u;
  int sidx[64], ridx[64];
};  // 23.0 KB -> 6 blocks/CU (LDS would allow 7)

__global__ __launch_bounds__(256, 6) void edge_mfma(
    const u16* __restrict__ rnb, const u16* __restrict__ pnb,
    const float* __restrict__ efeat, const int* __restrict__ senders,
    const int* __restrict__ receivers, EWb w, const u16* __restrict__ wb,
    const float* __restrict__ ss, u16* __restrict__ aggb, float* __restrict__ cnt) {
  __shared__ EdgeSmem sm;
  const int t = threadIdx.x, wv = t >> 6, lane = t & 63, l16 = lane & 15, quad = lane >> 4;
  const int cw = wv * 32;          // column strip base
  const int b  = blockIdx.y;
  const int e0 = blockIdx.x * 64;

  // ---- stage indices + zero-padded bf16 edge features ----
  if (t < 64) {
    sm.sidx[t] = min(max(senders[(size_t)b * cE + e0 + t], 0), cNR - 1);
    sm.ridx[t] = min(max(receivers[(size_t)b * cE + e0 + t], 0), cNP - 1);
    float4 ef = *(const float4*)(efeat + ((size_t)b * cE + e0 + t) * 4);
    uint4 w0 = { pack2(ef.x, ef.y), pack2(ef.z, ef.w), 0u, 0u };
    uint4 zz = { 0u, 0u, 0u, 0u };
    uint4* rowp = (uint4*)(sm.u.ef + (size_t)t * EFP);
    rowp[0] = w0; rowp[1] = zz; rowp[2] = zz; rowp[3] = zz; rowp[4] = zz;
  }
  __syncthreads();  // b1

  f32x4 acc[4][2];

  // ---- embed L1 via MFMA (K=32 zero-padded) + swish -> X ----
  init_acc_s(acc, w.be1, cw, l16);
  {
    const u16* wbe1 = wb + WB_WE1;
    s8v bf0 = *(const s8v*)(wbe1 + ((size_t)quad * 128 + cw + l16) * 8);
    s8v bf1 = *(const s8v*)(wbe1 + ((size_t)quad * 128 + cw + 16 + l16) * 8);
#pragma unroll
    for (int ri = 0; ri < 4; ++ri) {
      s8v af = *(const s8v*)(sm.u.ef + (size_t)(ri * 16 + l16) * EFP + quad * 8);
      acc[ri][0] = __builtin_amdgcn_mfma_f32_16x16x32_bf16(af, bf0, acc[ri][0], 0, 0, 0);
      acc[ri][1] = __builtin_amdgcn_mfma_f32_16x16x32_bf16(af, bf1, acc[ri][1], 0, 0, 0);
    }
  }
  store_s<true>(sm.bufX, acc, cw, l16, quad);   // h_embed
  __syncthreads();  // b2

  // ---- embed L2 + cond-norm(set0) -> e_emb packed into 16 regs ----
  init_acc_s(acc, w.be2, cw, l16);
  kloop128s(sm.bufX, wb + (size_t)G8_We2 * 1024, acc, cw, l16, quad);
  cond_norm_s(acc, sm.u.r.red, sm.u.r.musig, ss + (size_t)b * 256, cw, l16, quad, wv, t);
  unsigned e16[16];
#pragma unroll
  for (int ri = 0; ri < 4; ++ri)
#pragma unroll
    for (int reg = 0; reg < 4; ++reg)
      e16[ri * 4 + reg] = pack2(acc[ri][0][reg], acc[ri][1][reg]);

  // ---- update L1 (K=384 = sf|rf|e), sequenced through the single buffer ----
  // X is free: every wave's h_embed reads finished before cond_norm's first barrier.
#pragma unroll
  for (int rr = 0; rr < 16; ++rr) {   // sf: global->LDS DMA (bf16, 4B/lane)
    int row = wv * 16 + rr;
    gload4_lds(rnb + ((size_t)b * cNR + sm.sidx[row]) * cF + lane * 2,
               sm.bufX + (size_t)row * SP);
  }
  f32x4 accU[4][2];
  init_acc_s(accU, w.bu1, cw, l16);
  __syncthreads();  // b4: sf landed (syncthreads drains vmcnt incl. load_lds)
  kloop128s(sm.bufX, wb + (size_t)(G8_Wu1 + 16) * 1024, accU, cw, l16, quad);  // sf block
  __syncthreads();  // b5: sf reads done
#pragma unroll
  for (int rr = 0; rr < 16; ++rr) {   // rf: DMA from pre-converted bf16 pnode
    int row = wv * 16 + rr;
    gload4_lds(pnb + ((size_t)b * cNP + sm.ridx[row]) * cF + lane * 2,
               sm.bufX + (size_t)row * SP);
  }
  __syncthreads();  // b6: rf landed
  kloop128s(sm.bufX, wb + (size_t)(G8_Wu1 + 32) * 1024, accU, cw, l16, quad);  // rf block
  __syncthreads();  // b7: rf reads done
#pragma unroll
  for (int ri = 0; ri < 4; ++ri)      // e_emb -> X from regs
#pragma unroll
    for (int reg = 0; reg < 4; ++reg) {
      int row = ri * 16 + quad * 4 + reg;
      unsigned pw = e16[ri * 4 + reg];
      sm.bufX[(size_t)row * SP + cw + l16]      = (u16)(pw & 0xffffu);
      sm.bufX[(size_t)row * SP + cw + 16 + l16] = (u16)(pw >> 16);
    }
  __syncthreads();  // b8: e_emb visible
  kloop128s(sm.bufX, wb + (size_t)G8_Wu1 * 1024, accU, cw, l16, quad);         // e block
  __syncthreads();  // b9: e reads done
  store_s<true>(sm.bufX, accU, cw, l16, quad);  // h2
  __syncthreads();  // b10

  // ---- update L2 + cond-norm(set1) ----
  init_acc_s(acc, w.bu2, cw, l16);
  kloop128s(sm.bufX, wb + (size_t)G8_Wu2 * 1024, acc, cw, l16, quad);
  cond_norm_s(acc, sm.u.r.red, sm.u.r.musig, ss + (size_t)(cB + b) * 256, cw, l16, quad, wv, t);

  // ---- e = e_emb + u ; packed-bf16 segment-sum atomics ----
#pragma unroll
  for (int ri = 0; ri < 4; ++ri)
#pragma unroll
    for (int reg = 0; reg < 4; ++reg) {
      int row = ri * 16 + quad * 4 + reg;
      size_t rbase = ((size_t)b * cNP + sm.ridx[row]) * cF;
      unsigned pw = e16[ri * 4 + reg];
#pragma unroll
      for (int ci = 0; ci < 2; ++ci) {
        float ev = bf2f(ci ? (u16)(pw >> 16) : (u16)(pw & 0xffffu));
        float v = acc[ri][ci][reg] + ev;
        float vo = dpp_xor1(v);
        if (!(lane & 1)) atomic_pk_bf16(aggb + rbase + (cw + ci * 16 + l16), v, vo);
      }
    }
  if (t < 64) atomicAdd(cnt + (size_t)b * cNP + sm.ridx[t], 1.0f);
}

// ---------------- fused MFMA pnode pipeline (unchanged this round) ----------------
struct PWb { const float *bp1, *bp2, *bo1, *bo2; };

struct __align__(16) PnodeSmem {
  u16 bufP[64 * SP];   // pf -> p_new
  u16 bufX[64 * SP];   // mean -> h1 -> h_out
  float red[512];
  float musig[128];
  float cinv[64];
};  // ~37.6 KB -> 4 blocks/CU

__global__ __launch_bounds__(256, 4) void pnode_mfma(
    const float* __restrict__ pnode, PWb w, const u16* __restrict__ wb,
    const float* __restrict__ ss, const u16* __restrict__ aggb,
    const float* __restrict__ cnt, float* __restrict__ out) {
  __shared__ PnodeSmem sm;
  const int t = threadIdx.x, wv = t >> 6, lane = t & 63, l16 = lane & 15, quad = lane >> 4;
  const int cw = wv * 32;
  const int b  = blockIdx.y;
  const int n0 = blockIdx.x * 64;

  if (t < 64) sm.cinv[t] = __builtin_amdgcn_rcpf(fmaxf(cnt[(size_t)b * cNP + n0 + t], 1.0f));
  __syncthreads();  // b1

#pragma unroll
  for (int rr = 0; rr < 16; ++rr) {
    int row = wv * 16 + rr;
    float2 pv = *(const float2*)(pnode + ((size_t)b * cNP + n0 + row) * cF + lane * 2);
    unsigned avu = *(const unsigned*)(aggb + (((size_t)b * cNP + n0 + row) * cF + lane * 2));
    float ci_ = sm.cinv[row];
    float a0 = bf2f((u16)(avu & 0xffffu)) * ci_;
    float a1 = bf2f((u16)(avu >> 16)) * ci_;
    *(unsigned*)(sm.bufP + (size_t)row * SP + lane * 2) = pack2(pv.x, pv.y);
    *(unsigned*)(sm.bufX + (size_t)row * SP + lane * 2) = pack2(a0, a1);
  }
  __syncthreads();  // b2

  f32x4 acc[4][2];

  // ---- pnode L1: K=256 over [pf|mean] ----
  init_acc_s(acc, w.bp1, cw, l16);
  kloop128s(sm.bufP, wb + (size_t)G8_Wp1 * 1024, acc, cw, l16, quad);
  kloop128s(sm.bufX, wb + (size_t)(G8_Wp1 + 16) * 1024, acc, cw, l16, quad);
  __syncthreads();  // b3: all waves done reading bufX(mean)
  store_s<true>(sm.bufX, acc, cw, l16, quad);  // h1
  __syncthreads();  // b4

  // ---- pnode L2 + cond-norm(set2) + residual -> bufP ----
  init_acc_s(acc, w.bp2, cw, l16);
  kloop128s(sm.bufX, wb + (size_t)G8_Wp2 * 1024, acc, cw, l16, quad);
  cond_norm_s(acc, sm.red, sm.musig, ss + (size_t)(2 * cB + b) * 256, cw, l16, quad, wv, t);
#pragma unroll
  for (int ri = 0; ri < 4; ++ri)
#pragma unroll
    for (int reg = 0; reg < 4; ++reg) {
      int row = ri * 16 + quad * 4 + reg;
#pragma unroll
      for (int ci = 0; ci < 2; ++ci)
        acc[ri][ci][reg] += bf2f(sm.bufP[(size_t)row * SP + cw + ci * 16 + l16]);
    }
  __syncthreads();  // b5: all waves done residual-reading bufP
  store_s<false>(sm.bufP, acc, cw, l16, quad);  // p_new
  __syncthreads();  // b6

  // ---- output L1: K=128 -> bufX ----
  init_acc_s(acc, w.bo1, cw, l16);
  kloop128s(sm.bufP, wb + (size_t)G8_Wo1 * 1024, acc, cw, l16, quad);
  store_s<true>(sm.bufX, acc, cw, l16, quad);
  __syncthreads();  // b7

  // ---- output L2 via MFMA: K=128, N=16 (4 used) ----
  {
    const u16* wo2 = wb + (size_t)G8_TOT * 1024;
    float bv = (l16 < 4) ? w.bo2[l16] : 0.0f;
    f32x4 a1 = {bv, bv, bv, bv};
#pragma unroll
    for (int k0 = 0; k0 < 4; ++k0) {
      s8v af = *(const s8v*)(sm.bufX + (size_t)(wv * 16 + l16) * SP + k0 * 32 + quad * 8);
      s8v bf = *(const s8v*)(wo2 + ((size_t)(k0 * 4 + quad) * 16 + l16) * 8);
      a1 = __builtin_amdgcn_mfma_f32_16x16x32_bf16(af, bf, a1, 0, 0, 0);
    }
    if (l16 < 4) {
      size_t obase = (size_t)b * cNP + n0 + wv * 16 + quad * 4;
#pragma unroll
      for (int reg = 0; reg < 4; ++reg)
        out[(obase + reg) * 4 + l16] = a1[reg];
    }
  }
}

// ---------------- launch ----------------
extern "C" void kernel_launch(void* const* d_in, const int* in_sizes, int n_in,
                              void* d_out, int out_size, void* d_ws, size_t ws_size,
                              hipStream_t stream) {
  const float* rnode = (const float*)d_in[0];
  const float* pnode = (const float*)d_in[1];
  const float* efeat = (const float*)d_in[2];
  const float* tau   = (const float*)d_in[3];
  const int* senders   = (const int*)d_in[40];
  const int* receivers = (const int*)d_in[41];
  float* ws = (float*)d_ws;
  u16* aggb = (u16*)d_ws;                 // bf16 [B][NP][128]
  u16* wb   = (u16*)(ws + WS_WB);
  u16* rnb  = (u16*)(ws + WS_RB);         // bf16 rnode copy
  u16* pnb  = (u16*)(ws + WS_PB);         // bf16 pnode copy

  SwzSrc sw;
  sw.p[0] = (const float*)d_in[5];   // We2
  sw.p[1] = (const float*)d_in[12];  // Wu1
  sw.p[2] = (const float*)d_in[13];  // Wu2
  sw.p[3] = (const float*)d_in[20];  // Wp1
  sw.p[4] = (const float*)d_in[21];  // Wp2
  sw.p[5] = (const float*)d_in[36];  // Wo1
  sw.p[6] = (const float*)d_in[4];   // We1 (K=4 -> 32 padded)
  swz_kernel<<<(SWZ_N + 255) / 256, 256, 0, stream>>>(sw, (const float*)d_in[37], wb);

  const int nrn2 = (int)((size_t)cB * cNR * cF / 2);
  cvtn_kernel<<<(nrn2 + 255) / 256, 256, 0, stream>>>(rnode, rnb, nrn2);
  const int npn2 = (int)((size_t)cB * cNP * cF / 2);
  cvtn_kernel<<<(npn2 + 255) / 256, 256, 0, stream>>>(pnode, pnb, npn2);

  cond_kernel<<<dim3(3, cB), 256, 0, stream>>>(
      tau,
      (const float*)d_in[8],  (const float*)d_in[10],
      (const float*)d_in[9],  (const float*)d_in[11],
      (const float*)d_in[16], (const float*)d_in[18],
      (const float*)d_in[17], (const float*)d_in[19],
      (const float*)d_in[24], (const float*)d_in[26],
      (const float*)d_in[25], (const float*)d_in[27],
      ws + WS_SS);

  EWb ew = { (const float*)d_in[6], (const float*)d_in[7],
             (const float*)d_in[14], (const float*)d_in[15] };   // be1, be2, bu1, bu2
  PWb pw = { (const float*)d_in[22], (const float*)d_in[23], (const float*)d_in[38],
             (const float*)d_in[39] };                            // bp1, bp2, bo1, bo2

  const int n4 = (int)(WS_SS / 4);
  zero_kernel<<<(n4 + 255) / 256, 256, 0, stream>>>((float4*)ws, n4);

  edge_mfma<<<dim3(cE / 64, cB), 256, 0, stream>>>(
      rnb, pnb, efeat, senders, receivers, ew, wb,
      ws + WS_SS, aggb, ws + WS_CNT);

  pnode_mfma<<<dim3(cNP / 64, cB), 256, 0, stream>>>(
      pnode, pw, wb, ws + WS_SS, aggb, ws + WS_CNT,
      (float*)d_out);
}